// Round 2
// baseline (1049.304 us; speedup 1.0000x reference)
//
#include <hip/hip_runtime.h>
#include <hip/hip_bf16.h>

// Problem: B=2, S=2048, D=1024, H=16, DH=64. fp32 in/out (reference dtype).
#define S_LEN   2048
#define D_MODEL 1024
#define N_HEADS 16
#define D_HEAD  64
#define HEAD_ELEMS (2048ull * 64ull)          // elements per (b,h) plane
#define MAT_ELEMS  (4096ull * 1024ull)        // one projected matrix (Q or K or V)

// ---------------------------------------------------------------------------
// Kernel 1: QKV projection GEMM. C = x(4096x1024) @ W(1024x1024) fp32, written
// head-split as (b, h, s, dh) fp32 into workspace. grid (32, 8, 3), block 256.
// Tile 128x128, BK=32, 8x8 micro-tile per thread, fp32 LDS staging.
// ---------------------------------------------------------------------------
__global__ __launch_bounds__(256, 2) void qkv_gemm_kernel(
    const float* __restrict__ x,
    const float* __restrict__ Wq,
    const float* __restrict__ Wk,
    const float* __restrict__ Wv,
    float* __restrict__ qkv)
{
    const int mBlock = blockIdx.x * 128;
    const int nBlock = blockIdx.y * 128;
    const int which  = blockIdx.z;
    const float* W = (which == 0) ? Wq : (which == 1) ? Wk : Wv;
    float* outBase = qkv + (size_t)which * MAT_ELEMS;

    // [k][m] / [k][n]; stride 132 (mult of 4 -> float4-aligned rows, +4 breaks pow2)
    __shared__ float As[32][132];
    __shared__ float Bs[32][132];

    const int t  = threadIdx.x;
    const int tx = t & 15;   // n-direction
    const int ty = t >> 4;   // m-direction

    float acc[8][8];
#pragma unroll
    for (int i = 0; i < 8; ++i)
#pragma unroll
        for (int j = 0; j < 8; ++j) acc[i][j] = 0.f;

    for (int k0 = 0; k0 < D_MODEL; k0 += 32) {
        __syncthreads();
        {   // stage A tile (128 rows x 32 k), transposed into As[k][m]
            const int arow = t >> 1;          // 0..127
            const int acol = (t & 1) * 16;    // 0 or 16
            const float4* ap = (const float4*)(x + (size_t)(mBlock + arow) * D_MODEL + k0 + acol);
            float4 a0 = ap[0], a1 = ap[1], a2 = ap[2], a3 = ap[3];
            const float av[16] = {a0.x, a0.y, a0.z, a0.w, a1.x, a1.y, a1.z, a1.w,
                                  a2.x, a2.y, a2.z, a2.w, a3.x, a3.y, a3.z, a3.w};
#pragma unroll
            for (int i = 0; i < 16; ++i)
                As[acol + i][arow] = av[i];
        }
        {   // stage B tile (32 k x 128 n) into Bs[k][n], float4 stores
            const int brow = t >> 3;          // 0..31
            const int bcol = (t & 7) * 16;
            const float4* bp = (const float4*)(W + (size_t)(k0 + brow) * D_MODEL + nBlock + bcol);
#pragma unroll
            for (int i = 0; i < 4; ++i)
                *(float4*)&Bs[brow][bcol + 4 * i] = bp[i];
        }
        __syncthreads();
#pragma unroll 8
        for (int kk = 0; kk < 32; ++kk) {
            const float4 a0 = *(const float4*)&As[kk][ty * 8];
            const float4 a1 = *(const float4*)&As[kk][ty * 8 + 4];
            const float4 b0 = *(const float4*)&Bs[kk][tx * 4];
            const float4 b1 = *(const float4*)&Bs[kk][64 + tx * 4];
            const float a[8] = {a0.x, a0.y, a0.z, a0.w, a1.x, a1.y, a1.z, a1.w};
            const float b[8] = {b0.x, b0.y, b0.z, b0.w, b1.x, b1.y, b1.z, b1.w};
#pragma unroll
            for (int i = 0; i < 8; ++i)
#pragma unroll
                for (int j = 0; j < 8; ++j)
                    acc[i][j] += a[i] * b[j];
        }
    }

    // Epilogue: write head-split (b, h, s, dh) fp32; two float4 stores per row.
    const int nGrp0 = nBlock + tx * 4;
    const int nGrp1 = nBlock + 64 + tx * 4;
#pragma unroll
    for (int i = 0; i < 8; ++i) {
        const int mRow = mBlock + ty * 8 + i;
        const int bb = mRow >> 11;        // /2048
        const int ss = mRow & 2047;
        {
            const int h = nGrp0 >> 6, dh = nGrp0 & 63;
            float4 u = make_float4(acc[i][0], acc[i][1], acc[i][2], acc[i][3]);
            *(float4*)(outBase + ((size_t)(bb * N_HEADS + h) * S_LEN + ss) * D_HEAD + dh) = u;
        }
        {
            const int h = nGrp1 >> 6, dh = nGrp1 & 63;
            float4 u = make_float4(acc[i][4], acc[i][5], acc[i][6], acc[i][7]);
            *(float4*)(outBase + ((size_t)(bb * N_HEADS + h) * S_LEN + ss) * D_HEAD + dh) = u;
        }
    }
}

// ---------------------------------------------------------------------------
// Kernel 2: causal flash attention, fp32. grid (B*H=32, S/16=128), block 256.
// 4 waves/block, each wave owns 4 consecutive q-rows (lane d holds acc[d]).
// K tile [64 keys][64 d] and V^T tile [64 d][64 keys] staged in LDS fp32.
// ---------------------------------------------------------------------------
__global__ __launch_bounds__(256, 2) void attn_kernel(
    const float* __restrict__ qkv,
    float* __restrict__ out)
{
    const int bh   = blockIdx.x;          // 0..31  (b*16 + h)
    const int base = blockIdx.y * 16;     // first q-row of this block
    const int t    = threadIdx.x;
    const int w    = t >> 6;              // wave 0..3
    const int lane = t & 63;

    const float* Q = qkv + (size_t)bh * HEAD_ELEMS;
    const float* K = qkv + MAT_ELEMS + (size_t)bh * HEAD_ELEMS;
    const float* V = qkv + 2 * MAT_ELEMS + (size_t)bh * HEAD_ELEMS;

    __shared__ float Ks[64][65];   // [key][d]   (stride 65 -> 2-way, free)
    __shared__ float Vt[64][65];   // [d][key]
    __shared__ float qs[16][64];   // q rows, pre-scaled by 1/sqrt(64)
    __shared__ float ps[16][64];   // softmax probs per row

    {   // load 16 q rows, fold in 1/sqrt(DH)=0.125
        const int row = t >> 4;           // 0..15
        const int col = (t & 15) * 4;
        float4 u = *(const float4*)(Q + (size_t)(base + row) * D_HEAD + col);
        qs[row][col + 0] = u.x * 0.125f;
        qs[row][col + 1] = u.y * 0.125f;
        qs[row][col + 2] = u.z * 0.125f;
        qs[row][col + 3] = u.w * 0.125f;
    }

    const int r0 = base + w * 4;          // this wave's first q-row
    float mval[4], lval[4], accd[4];
#pragma unroll
    for (int i = 0; i < 4; ++i) { mval[i] = -__builtin_inff(); lval[i] = 0.f; accd[i] = 0.f; }

    const int nTiles = (base + 15) / 64 + 1;
    for (int tile = 0; tile < nTiles; ++tile) {
        const int j0 = tile * 64;
        __syncthreads();
        {   // stage K tile and transposed V tile
            const int row = t >> 2;           // 0..63 (key index within tile)
            const int col = (t & 3) * 16;     // d offset
            const float4* kp = (const float4*)(K + (size_t)(j0 + row) * D_HEAD + col);
            const float4* vp = (const float4*)(V + (size_t)(j0 + row) * D_HEAD + col);
#pragma unroll
            for (int i = 0; i < 4; ++i) {
                float4 kv = kp[i];
                float4 vv = vp[i];
                Ks[row][col + 4 * i + 0] = kv.x;
                Ks[row][col + 4 * i + 1] = kv.y;
                Ks[row][col + 4 * i + 2] = kv.z;
                Ks[row][col + 4 * i + 3] = kv.w;
                Vt[col + 4 * i + 0][row] = vv.x;
                Vt[col + 4 * i + 1][row] = vv.y;
                Vt[col + 4 * i + 2][row] = vv.z;
                Vt[col + 4 * i + 3][row] = vv.w;
            }
        }
        __syncthreads();

        if (j0 <= r0 + 3) {   // wave-uniform: this wave still has causal work
            // phase 1: lane j computes raw scores for key j0+lane, 4 rows
            float s[4] = {0.f, 0.f, 0.f, 0.f};
#pragma unroll
            for (int d4 = 0; d4 < 16; ++d4) {
                const int d = d4 * 4;
                const float kv0 = Ks[lane][d + 0];
                const float kv1 = Ks[lane][d + 1];
                const float kv2 = Ks[lane][d + 2];
                const float kv3 = Ks[lane][d + 3];
#pragma unroll
                for (int i = 0; i < 4; ++i) {
                    const float4 q = *(const float4*)&qs[w * 4 + i][d];
                    s[i] += q.x * kv0 + q.y * kv1 + q.z * kv2 + q.w * kv3;
                }
            }
            const int jg = j0 + lane;
#pragma unroll
            for (int i = 0; i < 4; ++i) {
                const int r = r0 + i;
                float si = (jg <= r) ? s[i] : -__builtin_inff();
                float mt = si;
#pragma unroll
                for (int off = 32; off >= 1; off >>= 1)
                    mt = fmaxf(mt, __shfl_xor(mt, off));
                const float mnew  = fmaxf(mval[i], mt);      // finite: tile 0 always valid
                const float p     = __expf(si - mnew);
                const float alpha = __expf(mval[i] - mnew);
                float ls = p;
#pragma unroll
                for (int off = 32; off >= 1; off >>= 1)
                    ls += __shfl_xor(ls, off);
                lval[i] = lval[i] * alpha + ls;
                accd[i] *= alpha;
                mval[i] = mnew;
                ps[w * 4 + i][lane] = p;   // same-wave write->read, no barrier needed
            }
            // phase 2: lane d accumulates ctx[row][d] += p[row][j] * V[j][d]
#pragma unroll
            for (int j4 = 0; j4 < 16; ++j4) {
                const int j = j4 * 4;
                const float vv0 = Vt[lane][j + 0];
                const float vv1 = Vt[lane][j + 1];
                const float vv2 = Vt[lane][j + 2];
                const float vv3 = Vt[lane][j + 3];
#pragma unroll
                for (int i = 0; i < 4; ++i) {
                    const float4 p4 = *(const float4*)&ps[w * 4 + i][j];
                    accd[i] += p4.x * vv0 + p4.y * vv1 + p4.z * vv2 + p4.w * vv3;
                }
            }
        }
    }

    // epilogue: out is (b, s, h*64+dh) fp32
    const int bb = bh >> 4;
    const int hh = bh & 15;
#pragma unroll
    for (int i = 0; i < 4; ++i) {
        const int r = r0 + i;
        out[((size_t)(bb * S_LEN + r)) * D_MODEL + hh * D_HEAD + lane] =
            accd[i] / lval[i];
    }
}

// ---------------------------------------------------------------------------
extern "C" void kernel_launch(void* const* d_in, const int* in_sizes, int n_in,
                              void* d_out, int out_size, void* d_ws, size_t ws_size,
                              hipStream_t stream) {
    const float* x  = (const float*)d_in[0];
    const float* Wq = (const float*)d_in[1];
    const float* Wk = (const float*)d_in[2];
    const float* Wv = (const float*)d_in[3];
    float* out = (float*)d_out;
    float* qkv = (float*)d_ws;   // needs 3*4096*1024*4 = 48 MB

    dim3 gGrid(4096 / 128, 1024 / 128, 3);         // (32, 8, 3)
    qkv_gemm_kernel<<<gGrid, 256, 0, stream>>>(x, Wq, Wk, Wv, qkv);

    dim3 aGrid(2 * N_HEADS, S_LEN / 16);           // (32, 128)
    attn_kernel<<<aGrid, 256, 0, stream>>>(qkv, out);
}

// Round 3
// 423.431 us; speedup vs baseline: 2.4781x; 2.4781x over previous
//
#include <hip/hip_runtime.h>
#include <hip/hip_bf16.h>

// Problem: B=2, S=2048, D=1024, H=16, DH=64. fp32 in/out.
// Internals: QKV projected in fp32, stored bf16; attention via bf16 MFMA.
#define S_LEN   2048
#define D_MODEL 1024
#define N_HEADS 16
#define D_HEAD  64
#define HEAD_ELEMS (2048ull * 64ull)          // elements per (b,h) plane
#define MAT_ELEMS  (4096ull * 1024ull)        // one projected matrix (Q or K or V)

typedef __attribute__((ext_vector_type(8))) short short8_t;   // 8 bf16 (4 VGPR)
typedef __attribute__((ext_vector_type(4))) short short4_t;   // 4 bf16 (8B)
typedef __attribute__((ext_vector_type(4))) float f32x4;      // MFMA C/D frag

__device__ __forceinline__ short f2bf(float f) {
    __hip_bfloat16 h = __float2bfloat16(f);
    union { __hip_bfloat16 h; short s; } cv;
    cv.h = h;
    return cv.s;
}

// ---------------------------------------------------------------------------
// Kernel 1: QKV projection GEMM (fp32 VALU core, unchanged from round 2).
// Epilogue: Q,K -> bf16 (b,h,s,dh); V -> bf16 TRANSPOSED (b,h,dh,s).
// grid (32, 8, 3), block 256. Tile 128x128, BK=32, 8x8 micro-tile.
// ---------------------------------------------------------------------------
__global__ __launch_bounds__(256, 2) void qkv_gemm_kernel(
    const float* __restrict__ x,
    const float* __restrict__ Wq,
    const float* __restrict__ Wk,
    const float* __restrict__ Wv,
    short* __restrict__ qkv)
{
    const int mBlock = blockIdx.x * 128;
    const int nBlock = blockIdx.y * 128;
    const int which  = blockIdx.z;
    const float* W = (which == 0) ? Wq : (which == 1) ? Wk : Wv;
    short* outBase = qkv + (size_t)which * MAT_ELEMS;

    __shared__ float As[32][132];   // [k][m]
    __shared__ float Bs[32][132];   // [k][n]

    const int t  = threadIdx.x;
    const int tx = t & 15;   // n-direction
    const int ty = t >> 4;   // m-direction

    float acc[8][8];
#pragma unroll
    for (int i = 0; i < 8; ++i)
#pragma unroll
        for (int j = 0; j < 8; ++j) acc[i][j] = 0.f;

    for (int k0 = 0; k0 < D_MODEL; k0 += 32) {
        __syncthreads();
        {   // stage A tile (128 rows x 32 k), transposed into As[k][m]
            const int arow = t >> 1;
            const int acol = (t & 1) * 16;
            const float4* ap = (const float4*)(x + (size_t)(mBlock + arow) * D_MODEL + k0 + acol);
            float4 a0 = ap[0], a1 = ap[1], a2 = ap[2], a3 = ap[3];
            const float av[16] = {a0.x, a0.y, a0.z, a0.w, a1.x, a1.y, a1.z, a1.w,
                                  a2.x, a2.y, a2.z, a2.w, a3.x, a3.y, a3.z, a3.w};
#pragma unroll
            for (int i = 0; i < 16; ++i)
                As[acol + i][arow] = av[i];
        }
        {   // stage B tile (32 k x 128 n) into Bs[k][n]
            const int brow = t >> 3;
            const int bcol = (t & 7) * 16;
            const float4* bp = (const float4*)(W + (size_t)(k0 + brow) * D_MODEL + nBlock + bcol);
#pragma unroll
            for (int i = 0; i < 4; ++i)
                *(float4*)&Bs[brow][bcol + 4 * i] = bp[i];
        }
        __syncthreads();
#pragma unroll 8
        for (int kk = 0; kk < 32; ++kk) {
            const float4 a0 = *(const float4*)&As[kk][ty * 8];
            const float4 a1 = *(const float4*)&As[kk][ty * 8 + 4];
            const float4 b0 = *(const float4*)&Bs[kk][tx * 4];
            const float4 b1 = *(const float4*)&Bs[kk][64 + tx * 4];
            const float a[8] = {a0.x, a0.y, a0.z, a0.w, a1.x, a1.y, a1.z, a1.w};
            const float b[8] = {b0.x, b0.y, b0.z, b0.w, b1.x, b1.y, b1.z, b1.w};
#pragma unroll
            for (int i = 0; i < 8; ++i)
#pragma unroll
                for (int j = 0; j < 8; ++j)
                    acc[i][j] += a[i] * b[j];
        }
    }

    if (which < 2) {
        // Q/K: (b,h,s,dh) bf16, two 8B stores per acc row.
#pragma unroll
        for (int i = 0; i < 8; ++i) {
            const int mRow = mBlock + ty * 8 + i;
            const int bb = mRow >> 11;
            const int ss = mRow & 2047;
            {
                const int n = nBlock + tx * 4;
                const int h = n >> 6, dh = n & 63;
                short4_t u;
                u[0] = f2bf(acc[i][0]); u[1] = f2bf(acc[i][1]);
                u[2] = f2bf(acc[i][2]); u[3] = f2bf(acc[i][3]);
                *(short4_t*)(outBase + ((size_t)(bb * N_HEADS + h) * S_LEN + ss) * D_HEAD + dh) = u;
            }
            {
                const int n = nBlock + 64 + tx * 4;
                const int h = n >> 6, dh = n & 63;
                short4_t u;
                u[0] = f2bf(acc[i][4]); u[1] = f2bf(acc[i][5]);
                u[2] = f2bf(acc[i][6]); u[3] = f2bf(acc[i][7]);
                *(short4_t*)(outBase + ((size_t)(bb * N_HEADS + h) * S_LEN + ss) * D_HEAD + dh) = u;
            }
        }
    } else {
        // V: transposed (b,h,dh,s) bf16. acc[0..7][j] are 8 consecutive s rows
        // (same bb: mBlock is 128-aligned, ty*8+7 < 128) -> one 16B store per j.
        const int mRow0 = mBlock + ty * 8;
        const int bb  = mRow0 >> 11;
        const int ss0 = mRow0 & 2047;
#pragma unroll
        for (int j = 0; j < 8; ++j) {
            const int n = nBlock + ((j < 4) ? (tx * 4 + j) : (64 + tx * 4 + (j - 4)));
            const int h = n >> 6, dh = n & 63;
            short8_t u;
#pragma unroll
            for (int i = 0; i < 8; ++i) u[i] = f2bf(acc[i][j]);
            *(short8_t*)(outBase + ((size_t)((bb * N_HEADS + h) * D_HEAD + dh)) * S_LEN + ss0) = u;
        }
    }
}

// ---------------------------------------------------------------------------
// Kernel 2: causal flash attention via bf16 MFMA (transposed formulation).
// grid (BH=32, S/64=32), block 256 = 4 waves; wave w owns q rows r0..r0+15.
//   St = K_tile(16x64) x Q^T        -> C frag: col=qrow(lane&15), row=key
//   softmax state per lane (one q-row per lane), P^T already in C layout
//   O^T = V^T_tile(16x64) x P^T     -> C frag: col=qrow, row=dh
// K LDS [key][d], V LDS [dh][key], both padded to 72 (144B rows: 16B-aligned,
// bank-balanced 8-access ds_read_b128 pattern). P round-trip is same-wave.
// ---------------------------------------------------------------------------
__global__ __launch_bounds__(256, 2) void attn_mfma_kernel(
    const short* __restrict__ qkv,
    float* __restrict__ out)
{
    const int bh   = blockIdx.x;          // b*16 + h
    const int qb   = blockIdx.y;          // q-block: rows [64*qb, 64*qb+64)
    const int base = qb * 64;
    const int t    = threadIdx.x;
    const int w    = t >> 6;              // wave 0..3
    const int lane = t & 63;
    const int n    = lane & 15;           // q-row within wave tile / M index
    const int quad = lane >> 4;           // 0..3

    const short* Q  = qkv + (size_t)bh * HEAD_ELEMS;
    const short* K  = qkv + MAT_ELEMS + (size_t)bh * HEAD_ELEMS;
    const short* Vt = qkv + 2 * MAT_ELEMS + (size_t)bh * HEAD_ELEMS;  // (dh,s)

    __shared__ __align__(16) short KsBuf[64][72];          // [key][d]
    __shared__ __align__(16) short VsBuf[64][72];          // [dh][key]
    __shared__ __align__(16) short PsBuf[4][16][72];       // per-wave [qrow][key]

    const int r0 = base + w * 16;
    const int qrow = r0 + n;              // this lane's global q-row

    // Q B-operand frags: B[k=d][n=qrow] = Q[qrow][d]; lane reads 8 consecutive d.
    const short8_t bq0 = *(const short8_t*)(Q + (size_t)qrow * D_HEAD + quad * 8);
    const short8_t bq1 = *(const short8_t*)(Q + (size_t)qrow * D_HEAD + quad * 8 + 32);

    float m = -__builtin_inff();
    float l = 0.f;
    f32x4 o[4];                            // O^T frags: dh groups 0,16,32,48
#pragma unroll
    for (int f = 0; f < 4; ++f) o[f] = (f32x4){0.f, 0.f, 0.f, 0.f};

    for (int tile = 0; tile <= qb; ++tile) {
        const int j0 = tile * 64;
        __syncthreads();                   // previous iter's LDS reads done
        {   // stage K tile (contiguous 8KB) and V^T tile
            const int row = t >> 2;        // key (for K) / dh (for V)
            const int seg = t & 3;         // 32B segment within 128B row
            const uint4* gk = (const uint4*)(K + (size_t)(j0 + row) * D_HEAD + seg * 16);
            uint4 k0 = gk[0], k1 = gk[1];
            *(uint4*)&KsBuf[row][seg * 16 + 0] = k0;
            *(uint4*)&KsBuf[row][seg * 16 + 8] = k1;
            const uint4* gv = (const uint4*)(Vt + (size_t)row * S_LEN + j0 + seg * 16);
            uint4 v0 = gv[0], v1 = gv[1];
            *(uint4*)&VsBuf[row][seg * 16 + 0] = v0;
            *(uint4*)&VsBuf[row][seg * 16 + 8] = v1;
        }
        __syncthreads();

        // ---- St = K_tile . Q^T : 4 key-groups x (K=64 as 2 chunks) ----
        f32x4 st[4];
#pragma unroll
        for (int kg = 0; kg < 4; ++kg) {
            const short8_t a0 = *(const short8_t*)&KsBuf[kg * 16 + n][quad * 8];
            const short8_t a1 = *(const short8_t*)&KsBuf[kg * 16 + n][quad * 8 + 32];
            f32x4 acc = (f32x4){0.f, 0.f, 0.f, 0.f};
            acc = __builtin_amdgcn_mfma_f32_16x16x32_bf16(a0, bq0, acc, 0, 0, 0);
            acc = __builtin_amdgcn_mfma_f32_16x16x32_bf16(a1, bq1, acc, 0, 0, 0);
            st[kg] = acc;
        }

        // ---- online softmax: one q-row per lane ----
        float p[16];
        float mx = -__builtin_inff();
#pragma unroll
        for (int kg = 0; kg < 4; ++kg) {
#pragma unroll
            for (int r = 0; r < 4; ++r) {
                const int key = j0 + kg * 16 + quad * 4 + r;
                float s = st[kg][r] * 0.125f;            // 1/sqrt(64)
                s = (key <= qrow) ? s : -__builtin_inff();
                p[kg * 4 + r] = s;
                mx = fmaxf(mx, s);
            }
        }
        mx = fmaxf(mx, __shfl_xor(mx, 16));
        mx = fmaxf(mx, __shfl_xor(mx, 32));
        const float mnew  = fmaxf(m, mx);                // finite (key 0 <= qrow)
        const float alpha = __expf(m - mnew);
        float ls = 0.f;
#pragma unroll
        for (int i = 0; i < 16; ++i) {
            p[i] = __expf(p[i] - mnew);
            ls += p[i];
        }
        ls += __shfl_xor(ls, 16);
        ls += __shfl_xor(ls, 32);
        l = l * alpha + ls;
        m = mnew;
#pragma unroll
        for (int f = 0; f < 4; ++f) {
            o[f][0] *= alpha; o[f][1] *= alpha; o[f][2] *= alpha; o[f][3] *= alpha;
        }

        // ---- P^T -> LDS (bf16), same-wave round trip (no barrier) ----
#pragma unroll
        for (int kg = 0; kg < 4; ++kg) {
            short4_t pk;
            pk[0] = f2bf(p[kg * 4 + 0]); pk[1] = f2bf(p[kg * 4 + 1]);
            pk[2] = f2bf(p[kg * 4 + 2]); pk[3] = f2bf(p[kg * 4 + 3]);
            *(short4_t*)&PsBuf[w][n][kg * 16 + quad * 4] = pk;
        }
        const short8_t pb0 = *(const short8_t*)&PsBuf[w][n][quad * 8];
        const short8_t pb1 = *(const short8_t*)&PsBuf[w][n][quad * 8 + 32];

        // ---- O^T += V^T_tile . P^T : 4 dh-groups x 2 chunks ----
#pragma unroll
        for (int f = 0; f < 4; ++f) {
            const short8_t va0 = *(const short8_t*)&VsBuf[f * 16 + n][quad * 8];
            const short8_t va1 = *(const short8_t*)&VsBuf[f * 16 + n][quad * 8 + 32];
            o[f] = __builtin_amdgcn_mfma_f32_16x16x32_bf16(va0, pb0, o[f], 0, 0, 0);
            o[f] = __builtin_amdgcn_mfma_f32_16x16x32_bf16(va1, pb1, o[f], 0, 0, 0);
        }
    }

    // ---- epilogue: O^T -> LDS transpose -> coalesced fp32 stores ----
    __syncthreads();   // all waves done with Ks/Vs; reuse as Os[4][16*72] floats
    float* Os = (float*)((w < 2) ? &KsBuf[0][0] : &VsBuf[0][0]) + (w & 1) * (16 * 72);
    const float inv_l = 1.0f / l;
#pragma unroll
    for (int f = 0; f < 4; ++f) {
        f32x4 q4;
        q4[0] = o[f][0] * inv_l; q4[1] = o[f][1] * inv_l;
        q4[2] = o[f][2] * inv_l; q4[3] = o[f][3] * inv_l;
        *(f32x4*)&Os[n * 72 + f * 16 + quad * 4] = q4;   // Os[qrow][dh]
    }
    // same-wave read-back, then coalesced 16B global stores
    const int bb = bh >> 4;
    const int hh = bh & 15;
#pragma unroll
    for (int rr = 0; rr < 4; ++rr) {
        const int row = rr * 4 + quad;                   // q-row within wave tile
        const f32x4 val = *(const f32x4*)&Os[row * 72 + n * 4];
        *(f32x4*)(out + ((size_t)(bb * S_LEN + r0 + row)) * D_MODEL + hh * D_HEAD + n * 4) = val;
    }
}

// ---------------------------------------------------------------------------
extern "C" void kernel_launch(void* const* d_in, const int* in_sizes, int n_in,
                              void* d_out, int out_size, void* d_ws, size_t ws_size,
                              hipStream_t stream) {
    const float* x  = (const float*)d_in[0];
    const float* Wq = (const float*)d_in[1];
    const float* Wk = (const float*)d_in[2];
    const float* Wv = (const float*)d_in[3];
    float* out = (float*)d_out;
    short* qkv = (short*)d_ws;   // bf16 workspace: 3*4096*1024*2 = 24 MB

    dim3 gGrid(4096 / 128, 1024 / 128, 3);         // (32, 8, 3)
    qkv_gemm_kernel<<<gGrid, 256, 0, stream>>>(x, Wq, Wk, Wv, qkv);

    dim3 aGrid(2 * N_HEADS, S_LEN / 64);           // (32, 32)
    attn_mfma_kernel<<<aGrid, 256, 0, stream>>>(qkv, out);
}

// Round 4
// 168.257 us; speedup vs baseline: 6.2363x; 2.5166x over previous
//
#include <hip/hip_runtime.h>
#include <hip/hip_bf16.h>

// B=2, S=2048, D=1024, H=16, DH=64. fp32 in/out; bf16 MFMA internals.
#define S_LEN   2048
#define D_MODEL 1024
#define N_HEADS 16
#define D_HEAD  64
#define HEAD_ELEMS (2048ull * 64ull)          // elements per (b,h) plane
#define MAT_ELEMS  (4096ull * 1024ull)        // one projected matrix (Q/K/V)
#define W_ELEMS    (1024ull * 1024ull)        // one weight matrix

typedef __attribute__((ext_vector_type(8))) short short8_t;   // 8 bf16
typedef __attribute__((ext_vector_type(4))) short short4_t;   // 4 bf16
typedef __attribute__((ext_vector_type(4))) float f32x4;      // MFMA C/D frag

__device__ __forceinline__ short f2bf(float f) {
    __hip_bfloat16 h = __float2bfloat16(f);
    union { __hip_bfloat16 h; short s; } cv;
    cv.h = h;
    return cv.s;
}

// global_load_lds width=16: LDS dest = wave-uniform base + lane*16
#define GLD_LDS16(gptr, lptr) \
    __builtin_amdgcn_global_load_lds( \
        (const __attribute__((address_space(1))) unsigned int*)(gptr), \
        (__attribute__((address_space(3))) unsigned int*)(lptr), 16, 0, 0)

// ---------------------------------------------------------------------------
// Kernel 0a: convert x fp32 -> bf16. 4096*1024 elems, 8/thread. grid 2048x256.
// ---------------------------------------------------------------------------
__global__ __launch_bounds__(256) void convert_x_kernel(
    const float* __restrict__ x, short* __restrict__ xb)
{
    const int i = (blockIdx.x * 256 + threadIdx.x) * 8;
    const float4 v0 = *(const float4*)(x + i);
    const float4 v1 = *(const float4*)(x + i + 4);
    short8_t u;
    u[0] = f2bf(v0.x); u[1] = f2bf(v0.y); u[2] = f2bf(v0.z); u[3] = f2bf(v0.w);
    u[4] = f2bf(v1.x); u[5] = f2bf(v1.y); u[6] = f2bf(v1.z); u[7] = f2bf(v1.w);
    *(short8_t*)(xb + i) = u;
}

// ---------------------------------------------------------------------------
// Kernel 0b: convert + transpose W fp32[k][n] -> bf16 Wt[n][k].
// grid (16,16,3), block 256, 64x64 tile via LDS.
// ---------------------------------------------------------------------------
__global__ __launch_bounds__(256) void transpose_w_kernel(
    const float* __restrict__ Wq, const float* __restrict__ Wk,
    const float* __restrict__ Wv, short* __restrict__ wt)
{
    const int k0 = blockIdx.x * 64;
    const int n0 = blockIdx.y * 64;
    const int which = blockIdx.z;
    const float* W = (which == 0) ? Wq : (which == 1) ? Wk : Wv;
    short* out = wt + (size_t)which * W_ELEMS;

    __shared__ float Ts[64][68];   // [n_local][k_local]
    const int t = threadIdx.x;
    {
        const int c4 = (t & 15) * 4;       // n_local
#pragma unroll
        for (int i = 0; i < 4; ++i) {
            const int r = (t >> 4) + i * 16;   // k_local
            const float4 v = *(const float4*)(W + (size_t)(k0 + r) * D_MODEL + n0 + c4);
            Ts[c4 + 0][r] = v.x; Ts[c4 + 1][r] = v.y;
            Ts[c4 + 2][r] = v.z; Ts[c4 + 3][r] = v.w;
        }
    }
    __syncthreads();
    const int nl = t >> 2;
#pragma unroll
    for (int s = 0; s < 2; ++s) {
        const int koff = (t & 3) * 8 + s * 32;
        short8_t u;
#pragma unroll
        for (int j = 0; j < 8; ++j) u[j] = f2bf(Ts[nl][koff + j]);
        *(short8_t*)(out + (size_t)(n0 + nl) * D_MODEL + k0 + koff) = u;
    }
}

// ---------------------------------------------------------------------------
// Kernel 1: QKV GEMM, m97 structure. C = xb(4096x1024) . Wt^T via bf16 MFMA.
// grid (32,8,3), block 256 = 4 waves. 128x128 tile, BK=32; wave = 64x64 quad,
// 4x4 16x16x32 acc frags. Staging via global_load_lds width 16 (contiguous
// LDS, no padding — required). Epilogue: Q/K (b,h,s,dh), V (b,h,dh,s) bf16.
// ---------------------------------------------------------------------------
__global__ __launch_bounds__(256, 3) void qkv_mfma_gemm_kernel(
    const short* __restrict__ xb,
    const short* __restrict__ wt,
    short* __restrict__ qkv)
{
    const int mBlock = blockIdx.x * 128;
    const int nBlock = blockIdx.y * 128;
    const int which  = blockIdx.z;
    const short* Bt = wt + (size_t)which * W_ELEMS;
    short* outBase  = qkv + (size_t)which * MAT_ELEMS;

    __shared__ short As[128 * 32];   // [m][k] contiguous, 8 KB
    __shared__ short Bs[128 * 32];   // [n][k] contiguous, 8 KB

    const int t    = threadIdx.x;
    const int w    = t >> 6;
    const int lane = t & 63;
    const int n16  = lane & 15;
    const int quad = lane >> 4;
    const int mq   = (w & 1) * 64;    // wave quadrant within 128x128
    const int nq   = (w >> 1) * 64;

    f32x4 acc[4][4];
#pragma unroll
    for (int i = 0; i < 4; ++i)
#pragma unroll
        for (int j = 0; j < 4; ++j) acc[i][j] = (f32x4){0.f, 0.f, 0.f, 0.f};

    // staging addresses: wave w stages bytes [w*2048, w*2048+2048) of each tile
    const int off0 = w * 2048 + lane * 16;       // bytes
    const int off1 = off0 + 1024;
    const int r0s = off0 >> 6, k0s = (off0 & 63) >> 1;   // row, k-shorts
    const int r1s = off1 >> 6, k1s = (off1 & 63) >> 1;
    const short* gA0 = xb + (size_t)(mBlock + r0s) * D_MODEL + k0s;
    const short* gA1 = xb + (size_t)(mBlock + r1s) * D_MODEL + k1s;
    const short* gB0 = Bt + (size_t)(nBlock + r0s) * D_MODEL + k0s;
    const short* gB1 = Bt + (size_t)(nBlock + r1s) * D_MODEL + k1s;
    short* lA0 = As + w * 1024;          // byte offset w*2048
    short* lA1 = As + w * 1024 + 512;    // +1024 bytes
    short* lB0 = Bs + w * 1024;
    short* lB1 = Bs + w * 1024 + 512;

    for (int k0 = 0; k0 < D_MODEL; k0 += 32) {
        __syncthreads();                 // prior iter's ds_reads done
        GLD_LDS16(gA0 + k0, lA0);
        GLD_LDS16(gA1 + k0, lA1);
        GLD_LDS16(gB0 + k0, lB0);
        GLD_LDS16(gB1 + k0, lB1);
        __syncthreads();                 // staging (vmcnt) drained

        short8_t af[4], bf[4];
#pragma unroll
        for (int mt = 0; mt < 4; ++mt)
            af[mt] = *(const short8_t*)&As[(mq + mt * 16 + n16) * 32 + quad * 8];
#pragma unroll
        for (int nt = 0; nt < 4; ++nt)
            bf[nt] = *(const short8_t*)&Bs[(nq + nt * 16 + n16) * 32 + quad * 8];
#pragma unroll
        for (int mt = 0; mt < 4; ++mt)
#pragma unroll
            for (int nt = 0; nt < 4; ++nt)
                acc[mt][nt] = __builtin_amdgcn_mfma_f32_16x16x32_bf16(
                    af[mt], bf[nt], acc[mt][nt], 0, 0, 0);
    }

    // Epilogue. C frag: m = quad*4+reg, n = lane&15 (m89-verified layout).
    if (which < 2) {
#pragma unroll
        for (int mt = 0; mt < 4; ++mt) {
#pragma unroll
            for (int nt = 0; nt < 4; ++nt) {
                const int n = nBlock + nq + nt * 16 + n16;
                const int h = n >> 6, dh = n & 63;
#pragma unroll
                for (int reg = 0; reg < 4; ++reg) {
                    const int m = mBlock + mq + mt * 16 + quad * 4 + reg;
                    const int bb = m >> 11, ss = m & 2047;
                    outBase[((size_t)(bb * N_HEADS + h) * S_LEN + ss) * D_HEAD + dh] =
                        f2bf(acc[mt][nt][reg]);
                }
            }
        }
    } else {
        // V transposed (b,h,dh,s): 4 regs = 4 consecutive s -> one 8B store
#pragma unroll
        for (int mt = 0; mt < 4; ++mt) {
            const int m0 = mBlock + mq + mt * 16 + quad * 4;
            const int bb = m0 >> 11, ss0 = m0 & 2047;
#pragma unroll
            for (int nt = 0; nt < 4; ++nt) {
                const int n = nBlock + nq + nt * 16 + n16;
                const int h = n >> 6, dh = n & 63;
                short4_t u;
                u[0] = f2bf(acc[mt][nt][0]); u[1] = f2bf(acc[mt][nt][1]);
                u[2] = f2bf(acc[mt][nt][2]); u[3] = f2bf(acc[mt][nt][3]);
                *(short4_t*)(outBase +
                    ((size_t)((bb * N_HEADS + h) * D_HEAD + dh)) * S_LEN + ss0) = u;
            }
        }
    }
}

// ---------------------------------------------------------------------------
// Kernel 2: causal flash attention via bf16 MFMA (unchanged from round 3).
// ---------------------------------------------------------------------------
__global__ __launch_bounds__(256, 2) void attn_mfma_kernel(
    const short* __restrict__ qkv,
    float* __restrict__ out)
{
    const int bh   = blockIdx.x;
    const int qb   = blockIdx.y;
    const int base = qb * 64;
    const int t    = threadIdx.x;
    const int w    = t >> 6;
    const int lane = t & 63;
    const int n    = lane & 15;
    const int quad = lane >> 4;

    const short* Q  = qkv + (size_t)bh * HEAD_ELEMS;
    const short* K  = qkv + MAT_ELEMS + (size_t)bh * HEAD_ELEMS;
    const short* Vt = qkv + 2 * MAT_ELEMS + (size_t)bh * HEAD_ELEMS;  // (dh,s)

    __shared__ __align__(16) short KsBuf[64][72];
    __shared__ __align__(16) short VsBuf[64][72];
    __shared__ __align__(16) short PsBuf[4][16][72];

    const int r0 = base + w * 16;
    const int qrow = r0 + n;

    const short8_t bq0 = *(const short8_t*)(Q + (size_t)qrow * D_HEAD + quad * 8);
    const short8_t bq1 = *(const short8_t*)(Q + (size_t)qrow * D_HEAD + quad * 8 + 32);

    float m = -__builtin_inff();
    float l = 0.f;
    f32x4 o[4];
#pragma unroll
    for (int f = 0; f < 4; ++f) o[f] = (f32x4){0.f, 0.f, 0.f, 0.f};

    for (int tile = 0; tile <= qb; ++tile) {
        const int j0 = tile * 64;
        __syncthreads();
        {
            const int row = t >> 2;
            const int seg = t & 3;
            const uint4* gk = (const uint4*)(K + (size_t)(j0 + row) * D_HEAD + seg * 16);
            uint4 k0 = gk[0], k1 = gk[1];
            *(uint4*)&KsBuf[row][seg * 16 + 0] = k0;
            *(uint4*)&KsBuf[row][seg * 16 + 8] = k1;
            const uint4* gv = (const uint4*)(Vt + (size_t)row * S_LEN + j0 + seg * 16);
            uint4 v0 = gv[0], v1 = gv[1];
            *(uint4*)&VsBuf[row][seg * 16 + 0] = v0;
            *(uint4*)&VsBuf[row][seg * 16 + 8] = v1;
        }
        __syncthreads();

        f32x4 st[4];
#pragma unroll
        for (int kg = 0; kg < 4; ++kg) {
            const short8_t a0 = *(const short8_t*)&KsBuf[kg * 16 + n][quad * 8];
            const short8_t a1 = *(const short8_t*)&KsBuf[kg * 16 + n][quad * 8 + 32];
            f32x4 acc = (f32x4){0.f, 0.f, 0.f, 0.f};
            acc = __builtin_amdgcn_mfma_f32_16x16x32_bf16(a0, bq0, acc, 0, 0, 0);
            acc = __builtin_amdgcn_mfma_f32_16x16x32_bf16(a1, bq1, acc, 0, 0, 0);
            st[kg] = acc;
        }

        float p[16];
        float mx = -__builtin_inff();
#pragma unroll
        for (int kg = 0; kg < 4; ++kg) {
#pragma unroll
            for (int r = 0; r < 4; ++r) {
                const int key = j0 + kg * 16 + quad * 4 + r;
                float s = st[kg][r] * 0.125f;
                s = (key <= qrow) ? s : -__builtin_inff();
                p[kg * 4 + r] = s;
                mx = fmaxf(mx, s);
            }
        }
        mx = fmaxf(mx, __shfl_xor(mx, 16));
        mx = fmaxf(mx, __shfl_xor(mx, 32));
        const float mnew  = fmaxf(m, mx);
        const float alpha = __expf(m - mnew);
        float ls = 0.f;
#pragma unroll
        for (int i = 0; i < 16; ++i) {
            p[i] = __expf(p[i] - mnew);
            ls += p[i];
        }
        ls += __shfl_xor(ls, 16);
        ls += __shfl_xor(ls, 32);
        l = l * alpha + ls;
        m = mnew;
#pragma unroll
        for (int f = 0; f < 4; ++f) {
            o[f][0] *= alpha; o[f][1] *= alpha; o[f][2] *= alpha; o[f][3] *= alpha;
        }

#pragma unroll
        for (int kg = 0; kg < 4; ++kg) {
            short4_t pk;
            pk[0] = f2bf(p[kg * 4 + 0]); pk[1] = f2bf(p[kg * 4 + 1]);
            pk[2] = f2bf(p[kg * 4 + 2]); pk[3] = f2bf(p[kg * 4 + 3]);
            *(short4_t*)&PsBuf[w][n][kg * 16 + quad * 4] = pk;
        }
        const short8_t pb0 = *(const short8_t*)&PsBuf[w][n][quad * 8];
        const short8_t pb1 = *(const short8_t*)&PsBuf[w][n][quad * 8 + 32];

#pragma unroll
        for (int f = 0; f < 4; ++f) {
            const short8_t va0 = *(const short8_t*)&VsBuf[f * 16 + n][quad * 8];
            const short8_t va1 = *(const short8_t*)&VsBuf[f * 16 + n][quad * 8 + 32];
            o[f] = __builtin_amdgcn_mfma_f32_16x16x32_bf16(va0, pb0, o[f], 0, 0, 0);
            o[f] = __builtin_amdgcn_mfma_f32_16x16x32_bf16(va1, pb1, o[f], 0, 0, 0);
        }
    }

    __syncthreads();
    float* Os = (float*)((w < 2) ? &KsBuf[0][0] : &VsBuf[0][0]) + (w & 1) * (16 * 72);
    const float inv_l = 1.0f / l;
#pragma unroll
    for (int f = 0; f < 4; ++f) {
        f32x4 q4;
        q4[0] = o[f][0] * inv_l; q4[1] = o[f][1] * inv_l;
        q4[2] = o[f][2] * inv_l; q4[3] = o[f][3] * inv_l;
        *(f32x4*)&Os[n * 72 + f * 16 + quad * 4] = q4;
    }
    const int bb = bh >> 4;
    const int hh = bh & 15;
#pragma unroll
    for (int rr = 0; rr < 4; ++rr) {
        const int row = rr * 4 + quad;
        const f32x4 val = *(const f32x4*)&Os[row * 72 + n * 4];
        *(f32x4*)(out + ((size_t)(bb * S_LEN + r0 + row)) * D_MODEL + hh * D_HEAD + n * 4) = val;
    }
}

// ---------------------------------------------------------------------------
extern "C" void kernel_launch(void* const* d_in, const int* in_sizes, int n_in,
                              void* d_out, int out_size, void* d_ws, size_t ws_size,
                              hipStream_t stream) {
    const float* x  = (const float*)d_in[0];
    const float* Wq = (const float*)d_in[1];
    const float* Wk = (const float*)d_in[2];
    const float* Wv = (const float*)d_in[3];
    float* out = (float*)d_out;

    // workspace: xb (8MB) | wt (6MB) | qkv (24MB) = 38MB
    short* xb  = (short*)d_ws;
    short* wt  = xb + MAT_ELEMS;
    short* qkv = wt + 3 * W_ELEMS;

    convert_x_kernel<<<dim3(MAT_ELEMS / (256 * 8)), 256, 0, stream>>>(x, xb);
    transpose_w_kernel<<<dim3(16, 16, 3), 256, 0, stream>>>(Wq, Wk, Wv, wt);

    qkv_mfma_gemm_kernel<<<dim3(32, 8, 3), 256, 0, stream>>>(xb, wt, qkv);

    attn_mfma_kernel<<<dim3(2 * N_HEADS, S_LEN / 64), 256, 0, stream>>>(qkv, out);
}

// Round 5
// 153.706 us; speedup vs baseline: 6.8267x; 1.0947x over previous
//
#include <hip/hip_runtime.h>
#include <hip/hip_bf16.h>

// B=2, S=2048, D=1024, H=16, DH=64. fp32 in/out; bf16 MFMA internals.
#define S_LEN   2048
#define D_MODEL 1024
#define N_HEADS 16
#define D_HEAD  64
#define HEAD_ELEMS (2048ull * 64ull)          // elements per (b,h) plane
#define MAT_ELEMS  (4096ull * 1024ull)        // one projected matrix (Q/K/V)
#define W_ELEMS    (1024ull * 1024ull)        // one weight matrix

typedef __attribute__((ext_vector_type(8))) short short8_t;   // 8 bf16
typedef __attribute__((ext_vector_type(4))) short short4_t;   // 4 bf16
typedef __attribute__((ext_vector_type(4))) float f32x4;      // MFMA C/D frag

__device__ __forceinline__ short f2bf(float f) {
    __hip_bfloat16 h = __float2bfloat16(f);
    union { __hip_bfloat16 h; short s; } cv;
    cv.h = h;
    return cv.s;
}

// global_load_lds width=16: LDS dest = wave-uniform base + lane*16
#define GLD_LDS16(gptr, lptr) \
    __builtin_amdgcn_global_load_lds( \
        (const __attribute__((address_space(1))) unsigned int*)(gptr), \
        (__attribute__((address_space(3))) unsigned int*)(lptr), 16, 0, 0)

// ---------------------------------------------------------------------------
// Kernel 0a: convert x fp32 -> bf16.
// ---------------------------------------------------------------------------
__global__ __launch_bounds__(256) void convert_x_kernel(
    const float* __restrict__ x, short* __restrict__ xb)
{
    const int i = (blockIdx.x * 256 + threadIdx.x) * 8;
    const float4 v0 = *(const float4*)(x + i);
    const float4 v1 = *(const float4*)(x + i + 4);
    short8_t u;
    u[0] = f2bf(v0.x); u[1] = f2bf(v0.y); u[2] = f2bf(v0.z); u[3] = f2bf(v0.w);
    u[4] = f2bf(v1.x); u[5] = f2bf(v1.y); u[6] = f2bf(v1.z); u[7] = f2bf(v1.w);
    *(short8_t*)(xb + i) = u;
}

// ---------------------------------------------------------------------------
// Kernel 0b: convert + transpose W fp32[k][n] -> bf16 Wt[n][k].
// ---------------------------------------------------------------------------
__global__ __launch_bounds__(256) void transpose_w_kernel(
    const float* __restrict__ Wq, const float* __restrict__ Wk,
    const float* __restrict__ Wv, short* __restrict__ wt)
{
    const int k0 = blockIdx.x * 64;
    const int n0 = blockIdx.y * 64;
    const int which = blockIdx.z;
    const float* W = (which == 0) ? Wq : (which == 1) ? Wk : Wv;
    short* out = wt + (size_t)which * W_ELEMS;

    __shared__ float Ts[64][68];   // [n_local][k_local]
    const int t = threadIdx.x;
    {
        const int c4 = (t & 15) * 4;
#pragma unroll
        for (int i = 0; i < 4; ++i) {
            const int r = (t >> 4) + i * 16;
            const float4 v = *(const float4*)(W + (size_t)(k0 + r) * D_MODEL + n0 + c4);
            Ts[c4 + 0][r] = v.x; Ts[c4 + 1][r] = v.y;
            Ts[c4 + 2][r] = v.z; Ts[c4 + 3][r] = v.w;
        }
    }
    __syncthreads();
    const int nl = t >> 2;
#pragma unroll
    for (int s = 0; s < 2; ++s) {
        const int koff = (t & 3) * 8 + s * 32;
        short8_t u;
#pragma unroll
        for (int j = 0; j < 8; ++j) u[j] = f2bf(Ts[nl][koff + j]);
        *(short8_t*)(out + (size_t)(n0 + nl) * D_MODEL + k0 + koff) = u;
    }
}

// ---------------------------------------------------------------------------
// Kernel 1: QKV GEMM (m97 structure, unchanged except Q pre-scaled by 0.125).
// ---------------------------------------------------------------------------
__global__ __launch_bounds__(256, 3) void qkv_mfma_gemm_kernel(
    const short* __restrict__ xb,
    const short* __restrict__ wt,
    short* __restrict__ qkv)
{
    const int mBlock = blockIdx.x * 128;
    const int nBlock = blockIdx.y * 128;
    const int which  = blockIdx.z;
    const short* Bt = wt + (size_t)which * W_ELEMS;
    short* outBase  = qkv + (size_t)which * MAT_ELEMS;

    __shared__ short As[128 * 32];   // [m][k] contiguous, 8 KB
    __shared__ short Bs[128 * 32];   // [n][k] contiguous, 8 KB

    const int t    = threadIdx.x;
    const int w    = t >> 6;
    const int lane = t & 63;
    const int n16  = lane & 15;
    const int quad = lane >> 4;
    const int mq   = (w & 1) * 64;
    const int nq   = (w >> 1) * 64;

    f32x4 acc[4][4];
#pragma unroll
    for (int i = 0; i < 4; ++i)
#pragma unroll
        for (int j = 0; j < 4; ++j) acc[i][j] = (f32x4){0.f, 0.f, 0.f, 0.f};

    const int off0 = w * 2048 + lane * 16;       // bytes
    const int off1 = off0 + 1024;
    const int r0s = off0 >> 6, k0s = (off0 & 63) >> 1;
    const int r1s = off1 >> 6, k1s = (off1 & 63) >> 1;
    const short* gA0 = xb + (size_t)(mBlock + r0s) * D_MODEL + k0s;
    const short* gA1 = xb + (size_t)(mBlock + r1s) * D_MODEL + k1s;
    const short* gB0 = Bt + (size_t)(nBlock + r0s) * D_MODEL + k0s;
    const short* gB1 = Bt + (size_t)(nBlock + r1s) * D_MODEL + k1s;
    short* lA0 = As + w * 1024;
    short* lA1 = As + w * 1024 + 512;
    short* lB0 = Bs + w * 1024;
    short* lB1 = Bs + w * 1024 + 512;

    for (int k0 = 0; k0 < D_MODEL; k0 += 32) {
        __syncthreads();
        GLD_LDS16(gA0 + k0, lA0);
        GLD_LDS16(gA1 + k0, lA1);
        GLD_LDS16(gB0 + k0, lB0);
        GLD_LDS16(gB1 + k0, lB1);
        __syncthreads();

        short8_t af[4], bf[4];
#pragma unroll
        for (int mt = 0; mt < 4; ++mt)
            af[mt] = *(const short8_t*)&As[(mq + mt * 16 + n16) * 32 + quad * 8];
#pragma unroll
        for (int nt = 0; nt < 4; ++nt)
            bf[nt] = *(const short8_t*)&Bs[(nq + nt * 16 + n16) * 32 + quad * 8];
#pragma unroll
        for (int mt = 0; mt < 4; ++mt)
#pragma unroll
            for (int nt = 0; nt < 4; ++nt)
                acc[mt][nt] = __builtin_amdgcn_mfma_f32_16x16x32_bf16(
                    af[mt], bf[nt], acc[mt][nt], 0, 0, 0);
    }

    const float oscale = (which == 0) ? 0.125f : 1.0f;   // fold 1/sqrt(DH) into Q
    if (which < 2) {
#pragma unroll
        for (int mt = 0; mt < 4; ++mt) {
#pragma unroll
            for (int nt = 0; nt < 4; ++nt) {
                const int n = nBlock + nq + nt * 16 + n16;
                const int h = n >> 6, dh = n & 63;
#pragma unroll
                for (int reg = 0; reg < 4; ++reg) {
                    const int m = mBlock + mq + mt * 16 + quad * 4 + reg;
                    const int bb = m >> 11, ss = m & 2047;
                    outBase[((size_t)(bb * N_HEADS + h) * S_LEN + ss) * D_HEAD + dh] =
                        f2bf(acc[mt][nt][reg] * oscale);
                }
            }
        }
    } else {
        // V transposed (b,h,dh,s)
#pragma unroll
        for (int mt = 0; mt < 4; ++mt) {
            const int m0 = mBlock + mq + mt * 16 + quad * 4;
            const int bb = m0 >> 11, ss0 = m0 & 2047;
#pragma unroll
            for (int nt = 0; nt < 4; ++nt) {
                const int n = nBlock + nq + nt * 16 + n16;
                const int h = n >> 6, dh = n & 63;
                short4_t u;
                u[0] = f2bf(acc[mt][nt][0]); u[1] = f2bf(acc[mt][nt][1]);
                u[2] = f2bf(acc[mt][nt][2]); u[3] = f2bf(acc[mt][nt][3]);
                *(short4_t*)(outBase +
                    ((size_t)((bb * N_HEADS + h) * D_HEAD + dh)) * S_LEN + ss0) = u;
            }
        }
    }
}

// ---------------------------------------------------------------------------
// Kernel 2: causal flash attention via bf16 MFMA, v3.
// grid (BH=32, 16 pairs): block handles q-tiles {p, 31-p} -> uniform 33 tiles.
// K/V staged via global_load_lds w/ XOR-swizzled LDS (chunk' = chunk^(row&7),
// swizzle applied to GLOBAL source addr so the lane-ordered DMA dest works).
// Mask only on the diagonal tile. Q pre-scaled by 1/8 in the GEMM.
// ---------------------------------------------------------------------------
__global__ __launch_bounds__(256, 2) void attn_mfma_kernel(
    const short* __restrict__ qkv,
    float* __restrict__ out)
{
    const int bh   = blockIdx.x;
    const int pr   = blockIdx.y;          // pair index 0..15
    const int t    = threadIdx.x;
    const int w    = t >> 6;
    const int lane = t & 63;
    const int n    = lane & 15;
    const int quad = lane >> 4;

    const short* Q  = qkv + (size_t)bh * HEAD_ELEMS;
    const short* K  = qkv + MAT_ELEMS + (size_t)bh * HEAD_ELEMS;
    const short* Vt = qkv + 2 * MAT_ELEMS + (size_t)bh * HEAD_ELEMS;  // (dh,s)

    __shared__ __align__(16) short Ks[64 * 64];          // swizzled [row][chunk]
    __shared__ __align__(16) short Vs[64 * 64];          // swizzled [dh][chunk]
    __shared__ __align__(16) short Ps[4][16][72];        // per-wave P round-trip

    // --- staging: wave w stages rows [16w,16w+16) of K and V, 2 insts each ---
    const int srow0 = w * 16 + (lane >> 3);              // inst-0 row
    const int srow1 = srow0 + 8;                         // inst-1 row
    const int sd0 = ((lane & 7) ^ (srow0 & 7)) * 8;      // swizzled src offset
    const int sd1 = ((lane & 7) ^ (srow1 & 7)) * 8;
    const short* gK0 = K + srow0 * 64 + sd0;             // += j0*64 per tile
    const short* gK1 = K + srow1 * 64 + sd1;
    const short* gV0 = Vt + (size_t)srow0 * S_LEN + sd0; // += j0 per tile
    const short* gV1 = Vt + (size_t)srow1 * S_LEN + sd1;
    short* lK0 = Ks + (w * 16) * 64;
    short* lK1 = Ks + (w * 16 + 8) * 64;
    short* lV0 = Vs + (w * 16) * 64;
    short* lV1 = Vs + (w * 16 + 8) * 64;

    // frag-read physical chunk offset (shorts): a0 at pcK, a1 at pcK^32
    const int pcK = ((quad ^ (n & 7))) * 8;

    const int bb = bh >> 4;
    const int hh = bh & 15;

    for (int pass = 0; pass < 2; ++pass) {
        const int qb = pass ? (31 - pr) : pr;
        const int r0 = qb * 64 + w * 16;
        const int qrow = r0 + n;

        const short8_t bq0 = *(const short8_t*)(Q + (size_t)qrow * D_HEAD + quad * 8);
        const short8_t bq1 = *(const short8_t*)(Q + (size_t)qrow * D_HEAD + quad * 8 + 32);

        float m = -__builtin_inff();
        float l = 0.f;
        f32x4 o[4];
#pragma unroll
        for (int f = 0; f < 4; ++f) o[f] = (f32x4){0.f, 0.f, 0.f, 0.f};

        for (int tile = 0; tile <= qb; ++tile) {
            const int j0 = tile * 64;
            __syncthreads();                       // prior LDS reads done
            GLD_LDS16(gK0 + j0 * 64, lK0);
            GLD_LDS16(gK1 + j0 * 64, lK1);
            GLD_LDS16(gV0 + j0, lV0);
            GLD_LDS16(gV1 + j0, lV1);
            __syncthreads();                       // vmcnt drained by barrier

            // ---- S^T = K_tile . Q^T (Q pre-scaled by 1/8) ----
            f32x4 st[4];
#pragma unroll
            for (int kg = 0; kg < 4; ++kg) {
                const int rbase = (kg * 16 + n) * 64;
                const short8_t a0 = *(const short8_t*)&Ks[rbase + pcK];
                const short8_t a1 = *(const short8_t*)&Ks[rbase + (pcK ^ 32)];
                f32x4 acc = (f32x4){0.f, 0.f, 0.f, 0.f};
                acc = __builtin_amdgcn_mfma_f32_16x16x32_bf16(a0, bq0, acc, 0, 0, 0);
                acc = __builtin_amdgcn_mfma_f32_16x16x32_bf16(a1, bq1, acc, 0, 0, 0);
                st[kg] = acc;
            }

            // ---- online softmax (mask only on diagonal tile) ----
            float p[16];
            float mx = -__builtin_inff();
            if (tile == qb) {
#pragma unroll
                for (int kg = 0; kg < 4; ++kg)
#pragma unroll
                    for (int r = 0; r < 4; ++r) {
                        const int key = j0 + kg * 16 + quad * 4 + r;
                        float s = st[kg][r];
                        s = (key <= qrow) ? s : -__builtin_inff();
                        p[kg * 4 + r] = s;
                        mx = fmaxf(mx, s);
                    }
            } else {
#pragma unroll
                for (int i = 0; i < 16; ++i) {
                    const float s = st[i >> 2][i & 3];
                    p[i] = s;
                    mx = fmaxf(mx, s);
                }
            }
            mx = fmaxf(mx, __shfl_xor(mx, 16));
            mx = fmaxf(mx, __shfl_xor(mx, 32));
            const float mnew  = fmaxf(m, mx);
            const float alpha = __expf(m - mnew);
            float ls = 0.f;
#pragma unroll
            for (int i = 0; i < 16; ++i) {
                p[i] = __expf(p[i] - mnew);
                ls += p[i];
            }
            ls += __shfl_xor(ls, 16);
            ls += __shfl_xor(ls, 32);
            l = l * alpha + ls;
            m = mnew;
#pragma unroll
            for (int f = 0; f < 4; ++f) {
                o[f][0] *= alpha; o[f][1] *= alpha; o[f][2] *= alpha; o[f][3] *= alpha;
            }

            // ---- pack P -> bf16 by truncation, same-wave LDS round trip ----
#pragma unroll
            for (int kg = 0; kg < 4; ++kg) {
                const unsigned int b0 = __builtin_bit_cast(unsigned int, p[kg * 4 + 0]);
                const unsigned int b1 = __builtin_bit_cast(unsigned int, p[kg * 4 + 1]);
                const unsigned int b2 = __builtin_bit_cast(unsigned int, p[kg * 4 + 2]);
                const unsigned int b3 = __builtin_bit_cast(unsigned int, p[kg * 4 + 3]);
                uint2 pk;
                pk.x = (b0 >> 16) | (b1 & 0xffff0000u);
                pk.y = (b2 >> 16) | (b3 & 0xffff0000u);
                *(uint2*)&Ps[w][n][kg * 16 + quad * 4] = pk;
            }
            const short8_t pb0 = *(const short8_t*)&Ps[w][n][quad * 8];
            const short8_t pb1 = *(const short8_t*)&Ps[w][n][quad * 8 + 32];

            // ---- O^T += V^T_tile . P^T ----
#pragma unroll
            for (int f = 0; f < 4; ++f) {
                const int rbase = (f * 16 + n) * 64;
                const short8_t va0 = *(const short8_t*)&Vs[rbase + pcK];
                const short8_t va1 = *(const short8_t*)&Vs[rbase + (pcK ^ 32)];
                o[f] = __builtin_amdgcn_mfma_f32_16x16x32_bf16(va0, pb0, o[f], 0, 0, 0);
                o[f] = __builtin_amdgcn_mfma_f32_16x16x32_bf16(va1, pb1, o[f], 0, 0, 0);
            }
        }

        // ---- epilogue: swizzled transpose through Ks/Vs, coalesced stores ----
        __syncthreads();   // all waves done reading Ks/Vs this pass
        float* Os = (float*)((w < 2) ? Ks : Vs) + (w & 1) * 1024;  // 16 rows x 64 f
        const float inv_l = 1.0f / l;
#pragma unroll
        for (int f = 0; f < 4; ++f) {
            const int c  = f * 4 + quad;          // logical 16B chunk (dh/4)
            const int pc = c ^ n;                 // physical chunk
            f32x4 q4;
            q4[0] = o[f][0] * inv_l; q4[1] = o[f][1] * inv_l;
            q4[2] = o[f][2] * inv_l; q4[3] = o[f][3] * inv_l;
            *(f32x4*)&Os[n * 64 + pc * 4] = q4;   // row n, dh chunk c
        }
#pragma unroll
        for (int rr = 0; rr < 4; ++rr) {
            const int row = rr * 4 + quad;        // q-row within wave tile
            const int pc  = n ^ row;              // logical chunk n, swizzled
            const f32x4 val = *(const f32x4*)&Os[row * 64 + pc * 4];
            *(f32x4*)(out + ((size_t)(bb * S_LEN + r0 + row)) * D_MODEL
                          + hh * D_HEAD + n * 4) = val;
        }
        // next pass's first tile starts with __syncthreads -> safe to restage
    }
}

// ---------------------------------------------------------------------------
extern "C" void kernel_launch(void* const* d_in, const int* in_sizes, int n_in,
                              void* d_out, int out_size, void* d_ws, size_t ws_size,
                              hipStream_t stream) {
    const float* x  = (const float*)d_in[0];
    const float* Wq = (const float*)d_in[1];
    const float* Wk = (const float*)d_in[2];
    const float* Wv = (const float*)d_in[3];
    float* out = (float*)d_out;

    // workspace: xb (8MB) | wt (6MB) | qkv (24MB) = 38MB
    short* xb  = (short*)d_ws;
    short* wt  = xb + MAT_ELEMS;
    short* qkv = wt + 3 * W_ELEMS;

    convert_x_kernel<<<dim3(MAT_ELEMS / (256 * 8)), 256, 0, stream>>>(x, xb);
    transpose_w_kernel<<<dim3(16, 16, 3), 256, 0, stream>>>(Wq, Wk, Wv, wt);

    qkv_mfma_gemm_kernel<<<dim3(32, 8, 3), 256, 0, stream>>>(xb, wt, qkv);

    attn_mfma_kernel<<<dim3(2 * N_HEADS, 16), 256, 0, stream>>>(qkv, out);
}